// Round 14
// baseline (465.655 us; speedup 1.0000x reference)
//
#include <hip/hip_runtime.h>
#include <hip/hip_fp16.h>

// GCN 3-layer encoder for MI355X — R14: R13 (410.7us) + k_bin at FULL
// occupancy. R13's k_bin ran 256 blocks = 4 waves/CU (12.5%) for a kernel
// streaming 19.2MB x2 + 3.2M LDS atomics -- likely latency-bound. R14: 2048
// blocks (8/CU; 16KB LDS allows 10). Tail atomics grow 390K -> ~1.26M but
// spread over 1563 words (R3's pathology was ballot serialization, not
// spread atomics). Everything else R13-exact.
// Layers (R13): gather T[16][128] in LDS -> MFMA U=T@W -> fused epilogue;
// associativity out = (S*A)*W + b deletes standalone gemms.
// k_pre -> k_bin -> k_fill(+As0) -> k_layer<W0> -> k_layer<W1> -> k_layer<W2>

typedef __attribute__((ext_vector_type(8))) _Float16 f16x8;
typedef __attribute__((ext_vector_type(4))) float f32x4;
typedef unsigned long long u64;

#define WQ_BITS 15
#define WQ_SCALE 32768.0f
#define WQ_MASK 32767u
#define MAXNP 2048
#define TSTR 136  // LDS T row stride in halfs (272B: 16B-aligned, non-pow2)

#define SHFLU(v, k) ((unsigned int)__shfl((int)(v), (k), 64))

// Fused: zero tails + transpose W0/W1/W2 (fp32 [k][n]) into f16 Wt [n][k].
__global__ __launch_bounds__(256) void k_pre(int* tail, int NP,
                                             const float* __restrict__ W0,
                                             const float* __restrict__ W1,
                                             const float* __restrict__ W2,
                                             __half* __restrict__ wt0,
                                             __half* __restrict__ wt1,
                                             __half* __restrict__ wt2) {
    int id = blockIdx.x * 256 + threadIdx.x;
    if (id < NP) tail[id] = 0;
    if (id < 16384) {
        int n = id >> 7, k = id & 127;
        wt0[id] = __float2half(W0[k * 128 + n]);
    } else if (id < 32768) {
        int j = id - 16384, n = j >> 7, k = j & 127;
        wt1[j] = __float2half(W1[k * 128 + n]);
    } else if (id < 40960) {
        int j = id - 32768, n = j >> 7, k = j & 127;  // n in [0,64)
        wt2[j] = __float2half(W2[k * 64 + n]);
    }
}

// Phase 1: bin edges into NP per-node-range lists. Two passes over a
// contiguous per-block chunk (2nd pass L2-hot). 2048 blocks = 8/CU.
__global__ __launch_bounds__(256) void k_bin(const int* __restrict__ src,
                                             const int* __restrict__ dst,
                                             const float* __restrict__ w,
                                             int* tail, u64* __restrict__ glist,
                                             int E, int ecap, int NP, int shift) {
    __shared__ unsigned int h[MAXNP];
    __shared__ int base[MAXNP];
    const int nb = gridDim.x;
    const int per = (E + nb - 1) / nb;
    const int e0 = blockIdx.x * per;
    const int e1 = (e0 + per < E) ? e0 + per : E;

    for (int i = threadIdx.x; i < NP; i += 256) h[i] = 0;
    __syncthreads();
    for (int e = e0 + (int)threadIdx.x; e < e1; e += 256) {
        int p = dst[e] >> shift;
        atomicAdd(&h[p], 1u);
    }
    __syncthreads();
    for (int i = threadIdx.x; i < NP; i += 256) {
        unsigned int c = h[i];
        base[i] = c ? atomicAdd(&tail[i], (int)c) : 0;
    }
    __syncthreads();
    for (int e = e0 + (int)threadIdx.x; e < e1; e += 256) {
        int t = dst[e];  // L2-hot (pass 1 cached it)
        int p = t >> shift;
        int s = __builtin_nontemporal_load(src + e);
        float we = __builtin_nontemporal_load(w + e);
        int wq = (int)(we * WQ_SCALE + 0.5f);
        wq = (wq < (int)WQ_MASK) ? wq : (int)WQ_MASK;
        u64 v = ((u64)(unsigned)t << 32) |
                ((unsigned)s << WQ_BITS) | (unsigned)wq;
        unsigned int idx = atomicSub(&h[p], 1u) - 1u;  // LDS, order-free
        int pos = base[p] + (int)idx;
        if (pos < ecap) glist[(size_t)p * ecap + pos] = v;
    }
}

// Phase 2: one block per 64-node partition. LDS slot counters; EW plain
// stores; cnt + dinv; then As0 = dinv * x as fp16 (the layer-0 prescaled
// input -- replaces the old fused gemm0 entirely).
__global__ __launch_bounds__(256) void k_fill(const int* __restrict__ tail,
                                              const u64* __restrict__ glist,
                                              int ecap, int* __restrict__ cnt,
                                              float* __restrict__ dinv,
                                              unsigned int* __restrict__ EW,
                                              int cap, int N, int shift,
                                              const float* __restrict__ X,
                                              __half* __restrict__ As0) {
    __shared__ unsigned int lcnt[MAXNP];
    __shared__ float lws[MAXNP];
    const int p = blockIdx.x;
    const int np = 1 << shift;
    const int t0 = p << shift;

    for (int i = threadIdx.x; i < np; i += 256) { lcnt[i] = 0; lws[i] = 0.f; }
    __syncthreads();
    int n = tail[p];
    if (n > ecap) n = ecap;
    const u64* L = glist + (size_t)p * ecap;
    for (int j = threadIdx.x; j < n; j += 256) {
        u64 v = L[j];
        int t = (int)(v >> 32);
        int loc = t - t0;
        unsigned int k = atomicAdd(&lcnt[loc], 1u);  // LDS
        if ((int)k < cap) {
            EW[(size_t)t * cap + k] = (unsigned int)v;
            atomicAdd(&lws[loc], (float)((unsigned int)v & WQ_MASK));  // LDS f32
        }
    }
    __syncthreads();
    for (int i = threadIdx.x; i < np; i += 256) {
        int t = t0 + i;
        float dv = 1.0f / sqrtf(1.0f + lws[i] * (1.0f / WQ_SCALE));
        if (t < N) {
            int c = (int)lcnt[i];
            c = (c < cap) ? c : cap;
            cnt[t] = c;
            dinv[t] = dv;
        }
        lws[i] = dv;  // hand dinv to the As0 stage via LDS
    }
    __syncthreads();

    // As0 = dinv * x (fp32 -> fp16), 4 threads per row, 32 cols each.
    for (int rb = 0; rb < np; rb += 64) {
        int rloc = rb + (int)(threadIdx.x >> 2);
        int sub = threadIdx.x & 3;
        int r = t0 + rloc;
        if (rloc < np && r < N) {
            float dv = lws[rloc];
#pragma unroll
            for (int cc = 0; cc < 4; cc++) {
                int c0 = sub * 32 + cc * 8;
                float4 u0 = *(const float4*)(X + (size_t)r * 128 + c0);
                float4 u1 = *(const float4*)(X + (size_t)r * 128 + c0 + 4);
                f16x8 f;
                f[0] = (_Float16)(dv * u0.x); f[1] = (_Float16)(dv * u0.y);
                f[2] = (_Float16)(dv * u0.z); f[3] = (_Float16)(dv * u0.w);
                f[4] = (_Float16)(dv * u1.x); f[5] = (_Float16)(dv * u1.y);
                f[6] = (_Float16)(dv * u1.z); f[7] = (_Float16)(dv * u1.w);
                *(f16x8*)(As0 + (size_t)r * 128 + c0) = f;
            }
        }
    }
}

// Fused layer: block = 16 nodes. Phase A: 4 waves gather T rows (R9 packed
// gather: 4 edges per dwordx4 instruction) into LDS. Phase B: MFMA U = T@W
// (k_gemm-verbatim fragment indexing; waves split columns) with fused
// epilogue: v = dt*U + b; [relu]; store fp16 dt*v (As_next) or fp32 v (out).
template <int BNO, bool RELU, bool FINAL>
__global__ __launch_bounds__(256) void k_layer(const __half* __restrict__ As,
                                               const unsigned int* __restrict__ EW,
                                               const int* __restrict__ cnt,
                                               const float* __restrict__ dinv,
                                               const __half* __restrict__ Wt,
                                               const float* __restrict__ bias,
                                               void* __restrict__ Outv,
                                               int N, int cap) {
    __shared__ __align__(16) __half T[16][TSTR];
    const int tid = threadIdx.x;
    const int lane = tid & 63;
    const int wv = tid >> 6;
    const int base = blockIdx.x * 16;

    // zero T (OOB rows must be 0 for the MFMA phase)
    for (int i = tid; i < 16 * TSTR; i += 256) ((__half*)T)[i] = (__half)0.f;
    __syncthreads();

    // ---- Phase A: gather. Wave wv owns nodes base + wv*4 + {0..3}. ----
    const int part = lane & 15;  // 16B chunk of the 256B row
    const int q = lane >> 4;     // edge within group of 4
    for (int i = 0; i < 4; i++) {
        const int rloc = wv * 4 + i;
        const int node = base + rloc;
        if (node < N) {
            int c = cnt[node];
            c = (c < cap) ? c : cap;
            unsigned int meta = 0;
            if (lane < c) meta = EW[(size_t)node * cap + lane];

            float acc[8];
#pragma unroll
            for (int j = 0; j < 8; j++) acc[j] = 0.f;

            int k = 0;
            for (; k + 16 <= c; k += 16) {
                f16x8 hv[4];
                float w[4];
#pragma unroll
                for (int g = 0; g < 4; g++) {
                    unsigned int mm = SHFLU(meta, k + g * 4 + q);
                    w[g] = (float)(mm & WQ_MASK) * (1.0f / WQ_SCALE);
                    hv[g] = *(const f16x8*)(As + (size_t)(mm >> WQ_BITS) * 128 + part * 8);
                }
#pragma unroll
                for (int g = 0; g < 4; g++)
#pragma unroll
                    for (int j = 0; j < 8; j++)
                        acc[j] = fmaf(w[g], (float)hv[g][j], acc[j]);
            }
            for (; k < c; k += 4) {
                int idx = k + q;
                unsigned int mm = SHFLU(meta, (idx < c) ? idx : 0);
                float w = (idx < c) ? (float)(mm & WQ_MASK) * (1.0f / WQ_SCALE) : 0.f;
                unsigned int row = (idx < c) ? (mm >> WQ_BITS) : (unsigned int)node;
                f16x8 hv = *(const f16x8*)(As + (size_t)row * 128 + part * 8);
#pragma unroll
                for (int j = 0; j < 8; j++)
                    acc[j] = fmaf(w, (float)hv[j], acc[j]);
            }
#pragma unroll
            for (int j = 0; j < 8; j++) {
                acc[j] += __shfl_xor(acc[j], 16, 64);
                acc[j] += __shfl_xor(acc[j], 32, 64);
            }
            if (q == 0) {
                f16x8 sv = *(const f16x8*)(As + (size_t)node * 128 + part * 8);
                f16x8 tv;
#pragma unroll
                for (int j = 0; j < 8; j++)
                    tv[j] = (_Float16)(acc[j] + (float)sv[j]);
                *(f16x8*)&T[rloc][part * 8] = tv;
            }
        }
    }
    __syncthreads();

    // ---- Phase B: U = T @ W via MFMA (k_gemm-verbatim indexing). ----
    const int m = lane & 15;
    const int quad = lane >> 4;
    constexpr int NT = (BNO == 128) ? 2 : 1;  // col-tiles per wave (x4 waves)

    f16x8 xf[4];
#pragma unroll
    for (int s = 0; s < 4; s++)
        xf[s] = *(const f16x8*)&T[m][s * 32 + quad * 8];

    f32x4 acc[NT];
#pragma unroll
    for (int t = 0; t < NT; t++) acc[t] = (f32x4){0.f, 0.f, 0.f, 0.f};

#pragma unroll
    for (int s = 0; s < 4; s++) {
#pragma unroll
        for (int t = 0; t < NT; t++) {
            const int ct = wv * NT + t;
            f16x8 wf = *(const f16x8*)(Wt + (size_t)(ct * 16 + m) * 128 + s * 32 + quad * 8);
            acc[t] = __builtin_amdgcn_mfma_f32_16x16x32_f16(wf, xf[s], acc[t], 0, 0, 0);
        }
    }

    const int row = base + m;
    if (row < N) {
        float dt = dinv[row];
#pragma unroll
        for (int t = 0; t < NT; t++) {
            const int ct = wv * NT + t;
            const int col0 = ct * 16 + quad * 4;
            f32x4 bv = *(const f32x4*)(bias + col0);
            float v0 = fmaf(dt, acc[t][0], bv[0]);
            float v1 = fmaf(dt, acc[t][1], bv[1]);
            float v2 = fmaf(dt, acc[t][2], bv[2]);
            float v3 = fmaf(dt, acc[t][3], bv[3]);
            if (RELU) {
                v0 = fmaxf(v0, 0.f); v1 = fmaxf(v1, 0.f);
                v2 = fmaxf(v2, 0.f); v3 = fmaxf(v3, 0.f);
            }
            if constexpr (!FINAL) {
                // store As_next = dt * relu(v) as fp16
                __half2 h0 = __floats2half2_rn(dt * v0, dt * v1);
                __half2 h1 = __floats2half2_rn(dt * v2, dt * v3);
                __half2* dstp = (__half2*)((__half*)Outv + (size_t)row * 128 + col0);
                dstp[0] = h0;
                dstp[1] = h1;
            } else {
                f32x4 o;
                o[0] = v0; o[1] = v1; o[2] = v2; o[3] = v3;
                *(f32x4*)((float*)Outv + (size_t)row * 64 + col0) = o;
            }
        }
    }
}

extern "C" void kernel_launch(void* const* d_in, const int* in_sizes, int n_in,
                              void* d_out, int out_size, void* d_ws, size_t ws_size,
                              hipStream_t stream) {
    const int N = in_sizes[0] / 128;   // x is [N,128]
    const int E = in_sizes[2];         // edge_weight is [E]

    const float* x  = (const float*)d_in[0];
    const int*   ei = (const int*)d_in[1];   // [2,E]: row0=src, row1=dst
    const int*   src = ei;
    const int*   dst = ei + E;
    const float* ew  = (const float*)d_in[2];
    const float* W0 = (const float*)d_in[3];
    const float* b0 = (const float*)d_in[4];
    const float* W1 = (const float*)d_in[5];
    const float* b1 = (const float*)d_in[6];
    const float* W2 = (const float*)d_in[7];
    const float* b2 = (const float*)d_in[8];

    // Partitioning: 64-node ranges; widen shift if N is huge so NP<=MAXNP.
    int shift = 6;
    while ((((N - 1) >> shift) + 1) > MAXNP) shift++;
    const int NP = ((N - 1) >> shift) + 1;

    // Workspace carve; bucket capacity adapts so we never write past d_ws.
    size_t fixed = (((size_t)N * 4 + 255) & ~(size_t)255)            // cnt
                 + (((size_t)N * 4 + 255) & ~(size_t)255)            // dinv
                 + 2 * (((size_t)N * 128 * 2 + 255) & ~(size_t)255)  // bufH, bufA fp16
                 + 3 * 33024                                         // wt0,wt1,wt2
                 + (((size_t)NP * 4 + 255) & ~(size_t)255)           // tail
                 + 2048;
    int cap = 64;
    if (ws_size > fixed) {
        size_t avail = (ws_size - fixed) / ((size_t)N * 4);
        if (avail < (size_t)cap) cap = (int)avail;
    } else {
        cap = 0;
    }

    char* p = (char*)d_ws;
    auto alloc = [&](size_t bytes) -> void* {
        void* r = (void*)p;
        p += (bytes + 255) & ~(size_t)255;
        return r;
    };
    int*          cnt  = (int*)alloc((size_t)N * 4);
    float*        dinv = (float*)alloc((size_t)N * 4);
    unsigned int* EW   = (unsigned int*)alloc((size_t)N * cap * 4);
    __half*       bufH = (__half*)alloc((size_t)N * 128 * 2);
    __half*       bufA = (__half*)alloc((size_t)N * 128 * 2);
    __half*       wt0  = (__half*)alloc(16384 * 2);
    __half*       wt1  = (__half*)alloc(16384 * 2);
    __half*       wt2  = (__half*)alloc(8192 * 2);
    int*          tail = (int*)alloc((size_t)NP * 4);

    // Bin lists alias bufA (dead after k_fill; layer-0 writes bufA).
    u64* glist = (u64*)bufA;
    int  ecap  = (int)(((size_t)N * 128 * 2) / ((size_t)NP * 8));  // ~2047 here

    dim3 blk(256);
    int preN = (NP > 40960) ? NP : 40960;
    dim3 gPre((preN + 255) / 256);
    dim3 gBin(2048);             // 8 blocks/CU (was 1): latency hiding
    dim3 gFill(NP);              // 1 block per 64-node partition
    dim3 gLayer((N + 15) / 16);  // 1 block per 16-node MFMA tile

    k_pre<<<gPre, blk, 0, stream>>>(tail, NP, W0, W1, W2, wt0, wt1, wt2);
    k_bin<<<gBin, blk, 0, stream>>>(src, dst, ew, tail, glist, E, ecap, NP, shift);
    k_fill<<<gFill, blk, 0, stream>>>(tail, glist, ecap, cnt, dinv, EW, cap, N,
                                      shift, x, bufH);

    // layer 0: gather(As0=bufH) -> @W0 -> As1=bufA
    k_layer<128, true, false><<<gLayer, blk, 0, stream>>>(bufH, EW, cnt, dinv,
                                                          wt0, b0, bufA, N, cap);
    // layer 1: gather(bufA) -> @W1 -> As2=bufH
    k_layer<128, true, false><<<gLayer, blk, 0, stream>>>(bufA, EW, cnt, dinv,
                                                          wt1, b1, bufH, N, cap);
    // layer 2: gather(bufH) -> @W2 -> out fp32 (no relu)
    k_layer<64, false, true><<<gLayer, blk, 0, stream>>>(bufH, EW, cnt, dinv,
                                                         wt2, b2, d_out, N, cap);
}

// Round 15
// 397.566 us; speedup vs baseline: 1.1713x; 1.1713x over previous
//
#include <hip/hip_runtime.h>
#include <hip/hip_fp16.h>

// GCN 3-layer encoder for MI355X — R15: R13 base (410.7us) + k_bin at
// 256 blocks x 1024 THREADS. R14 (2048x256: 465us, bin=113us) showed bin's
// cost scales with per-block FIXED work (zero+scan NP=1563 LDS histogram) --
// more blocks multiplied it 8x. This config keeps fixed work at R13's level
// (256 blocks) but 4x the waves/CU (4 -> 16; 12.5% -> 50% occupancy) for the
// latency-bound stream+LDS-atomic path. Tail atomics unchanged (~390K).
// Everything else R13-exact.
// Layers (R13): gather T[16][128] in LDS -> MFMA U=T@W -> fused epilogue;
// associativity out = (S*A)*W + b deletes standalone gemms.
// k_pre -> k_bin -> k_fill(+As0) -> k_layer<W0> -> k_layer<W1> -> k_layer<W2>

typedef __attribute__((ext_vector_type(8))) _Float16 f16x8;
typedef __attribute__((ext_vector_type(4))) float f32x4;
typedef unsigned long long u64;

#define WQ_BITS 15
#define WQ_SCALE 32768.0f
#define WQ_MASK 32767u
#define MAXNP 2048
#define TSTR 136  // LDS T row stride in halfs (272B: 16B-aligned, non-pow2)

#define SHFLU(v, k) ((unsigned int)__shfl((int)(v), (k), 64))

// Fused: zero tails + transpose W0/W1/W2 (fp32 [k][n]) into f16 Wt [n][k].
__global__ __launch_bounds__(256) void k_pre(int* tail, int NP,
                                             const float* __restrict__ W0,
                                             const float* __restrict__ W1,
                                             const float* __restrict__ W2,
                                             __half* __restrict__ wt0,
                                             __half* __restrict__ wt1,
                                             __half* __restrict__ wt2) {
    int id = blockIdx.x * 256 + threadIdx.x;
    if (id < NP) tail[id] = 0;
    if (id < 16384) {
        int n = id >> 7, k = id & 127;
        wt0[id] = __float2half(W0[k * 128 + n]);
    } else if (id < 32768) {
        int j = id - 16384, n = j >> 7, k = j & 127;
        wt1[j] = __float2half(W1[k * 128 + n]);
    } else if (id < 40960) {
        int j = id - 32768, n = j >> 7, k = j & 127;  // n in [0,64)
        wt2[j] = __float2half(W2[k * 64 + n]);
    }
}

// Phase 1: bin edges into NP per-node-range lists. 256 blocks (fixed NP
// work amortized once) x 1024 threads (16 waves/CU for latency hiding).
// Two passes over a contiguous per-block chunk (2nd pass L2-hot).
__global__ __launch_bounds__(1024) void k_bin(const int* __restrict__ src,
                                              const int* __restrict__ dst,
                                              const float* __restrict__ w,
                                              int* tail, u64* __restrict__ glist,
                                              int E, int ecap, int NP, int shift) {
    __shared__ unsigned int h[MAXNP];
    __shared__ int base[MAXNP];
    const int tid = threadIdx.x;
    const int nb = gridDim.x;
    const int per = (E + nb - 1) / nb;
    const int e0 = blockIdx.x * per;
    const int e1 = (e0 + per < E) ? e0 + per : E;

    for (int i = tid; i < NP; i += 1024) h[i] = 0;
    __syncthreads();
    for (int e = e0 + tid; e < e1; e += 1024) {
        int p = dst[e] >> shift;
        atomicAdd(&h[p], 1u);
    }
    __syncthreads();
    for (int i = tid; i < NP; i += 1024) {
        unsigned int c = h[i];
        base[i] = c ? atomicAdd(&tail[i], (int)c) : 0;
    }
    __syncthreads();
    for (int e = e0 + tid; e < e1; e += 1024) {
        int t = dst[e];  // L2-hot (pass 1 cached it)
        int p = t >> shift;
        int s = __builtin_nontemporal_load(src + e);
        float we = __builtin_nontemporal_load(w + e);
        int wq = (int)(we * WQ_SCALE + 0.5f);
        wq = (wq < (int)WQ_MASK) ? wq : (int)WQ_MASK;
        u64 v = ((u64)(unsigned)t << 32) |
                ((unsigned)s << WQ_BITS) | (unsigned)wq;
        unsigned int idx = atomicSub(&h[p], 1u) - 1u;  // LDS, order-free
        int pos = base[p] + (int)idx;
        if (pos < ecap) glist[(size_t)p * ecap + pos] = v;
    }
}

// Phase 2: one block per 64-node partition. LDS slot counters; EW plain
// stores; cnt + dinv; then As0 = dinv * x as fp16 (the layer-0 prescaled
// input -- replaces the old fused gemm0 entirely).
__global__ __launch_bounds__(256) void k_fill(const int* __restrict__ tail,
                                              const u64* __restrict__ glist,
                                              int ecap, int* __restrict__ cnt,
                                              float* __restrict__ dinv,
                                              unsigned int* __restrict__ EW,
                                              int cap, int N, int shift,
                                              const float* __restrict__ X,
                                              __half* __restrict__ As0) {
    __shared__ unsigned int lcnt[MAXNP];
    __shared__ float lws[MAXNP];
    const int p = blockIdx.x;
    const int np = 1 << shift;
    const int t0 = p << shift;

    for (int i = threadIdx.x; i < np; i += 256) { lcnt[i] = 0; lws[i] = 0.f; }
    __syncthreads();
    int n = tail[p];
    if (n > ecap) n = ecap;
    const u64* L = glist + (size_t)p * ecap;
    for (int j = threadIdx.x; j < n; j += 256) {
        u64 v = L[j];
        int t = (int)(v >> 32);
        int loc = t - t0;
        unsigned int k = atomicAdd(&lcnt[loc], 1u);  // LDS
        if ((int)k < cap) {
            EW[(size_t)t * cap + k] = (unsigned int)v;
            atomicAdd(&lws[loc], (float)((unsigned int)v & WQ_MASK));  // LDS f32
        }
    }
    __syncthreads();
    for (int i = threadIdx.x; i < np; i += 256) {
        int t = t0 + i;
        float dv = 1.0f / sqrtf(1.0f + lws[i] * (1.0f / WQ_SCALE));
        if (t < N) {
            int c = (int)lcnt[i];
            c = (c < cap) ? c : cap;
            cnt[t] = c;
            dinv[t] = dv;
        }
        lws[i] = dv;  // hand dinv to the As0 stage via LDS
    }
    __syncthreads();

    // As0 = dinv * x (fp32 -> fp16), 4 threads per row, 32 cols each.
    for (int rb = 0; rb < np; rb += 64) {
        int rloc = rb + (int)(threadIdx.x >> 2);
        int sub = threadIdx.x & 3;
        int r = t0 + rloc;
        if (rloc < np && r < N) {
            float dv = lws[rloc];
#pragma unroll
            for (int cc = 0; cc < 4; cc++) {
                int c0 = sub * 32 + cc * 8;
                float4 u0 = *(const float4*)(X + (size_t)r * 128 + c0);
                float4 u1 = *(const float4*)(X + (size_t)r * 128 + c0 + 4);
                f16x8 f;
                f[0] = (_Float16)(dv * u0.x); f[1] = (_Float16)(dv * u0.y);
                f[2] = (_Float16)(dv * u0.z); f[3] = (_Float16)(dv * u0.w);
                f[4] = (_Float16)(dv * u1.x); f[5] = (_Float16)(dv * u1.y);
                f[6] = (_Float16)(dv * u1.z); f[7] = (_Float16)(dv * u1.w);
                *(f16x8*)(As0 + (size_t)r * 128 + c0) = f;
            }
        }
    }
}

// Fused layer: block = 16 nodes. Phase A: 4 waves gather T rows (R9 packed
// gather: 4 edges per dwordx4 instruction) into LDS. Phase B: MFMA U = T@W
// (k_gemm-verbatim fragment indexing; waves split columns) with fused
// epilogue: v = dt*U + b; [relu]; store fp16 dt*v (As_next) or fp32 v (out).
template <int BNO, bool RELU, bool FINAL>
__global__ __launch_bounds__(256) void k_layer(const __half* __restrict__ As,
                                               const unsigned int* __restrict__ EW,
                                               const int* __restrict__ cnt,
                                               const float* __restrict__ dinv,
                                               const __half* __restrict__ Wt,
                                               const float* __restrict__ bias,
                                               void* __restrict__ Outv,
                                               int N, int cap) {
    __shared__ __align__(16) __half T[16][TSTR];
    const int tid = threadIdx.x;
    const int lane = tid & 63;
    const int wv = tid >> 6;
    const int base = blockIdx.x * 16;

    // zero T (OOB rows must be 0 for the MFMA phase)
    for (int i = tid; i < 16 * TSTR; i += 256) ((__half*)T)[i] = (__half)0.f;
    __syncthreads();

    // ---- Phase A: gather. Wave wv owns nodes base + wv*4 + {0..3}. ----
    const int part = lane & 15;  // 16B chunk of the 256B row
    const int q = lane >> 4;     // edge within group of 4
    for (int i = 0; i < 4; i++) {
        const int rloc = wv * 4 + i;
        const int node = base + rloc;
        if (node < N) {
            int c = cnt[node];
            c = (c < cap) ? c : cap;
            unsigned int meta = 0;
            if (lane < c) meta = EW[(size_t)node * cap + lane];

            float acc[8];
#pragma unroll
            for (int j = 0; j < 8; j++) acc[j] = 0.f;

            int k = 0;
            for (; k + 16 <= c; k += 16) {
                f16x8 hv[4];
                float w[4];
#pragma unroll
                for (int g = 0; g < 4; g++) {
                    unsigned int mm = SHFLU(meta, k + g * 4 + q);
                    w[g] = (float)(mm & WQ_MASK) * (1.0f / WQ_SCALE);
                    hv[g] = *(const f16x8*)(As + (size_t)(mm >> WQ_BITS) * 128 + part * 8);
                }
#pragma unroll
                for (int g = 0; g < 4; g++)
#pragma unroll
                    for (int j = 0; j < 8; j++)
                        acc[j] = fmaf(w[g], (float)hv[g][j], acc[j]);
            }
            for (; k < c; k += 4) {
                int idx = k + q;
                unsigned int mm = SHFLU(meta, (idx < c) ? idx : 0);
                float w = (idx < c) ? (float)(mm & WQ_MASK) * (1.0f / WQ_SCALE) : 0.f;
                unsigned int row = (idx < c) ? (mm >> WQ_BITS) : (unsigned int)node;
                f16x8 hv = *(const f16x8*)(As + (size_t)row * 128 + part * 8);
#pragma unroll
                for (int j = 0; j < 8; j++)
                    acc[j] = fmaf(w, (float)hv[j], acc[j]);
            }
#pragma unroll
            for (int j = 0; j < 8; j++) {
                acc[j] += __shfl_xor(acc[j], 16, 64);
                acc[j] += __shfl_xor(acc[j], 32, 64);
            }
            if (q == 0) {
                f16x8 sv = *(const f16x8*)(As + (size_t)node * 128 + part * 8);
                f16x8 tv;
#pragma unroll
                for (int j = 0; j < 8; j++)
                    tv[j] = (_Float16)(acc[j] + (float)sv[j]);
                *(f16x8*)&T[rloc][part * 8] = tv;
            }
        }
    }
    __syncthreads();

    // ---- Phase B: U = T @ W via MFMA (k_gemm-verbatim indexing). ----
    const int m = lane & 15;
    const int quad = lane >> 4;
    constexpr int NT = (BNO == 128) ? 2 : 1;  // col-tiles per wave (x4 waves)

    f16x8 xf[4];
#pragma unroll
    for (int s = 0; s < 4; s++)
        xf[s] = *(const f16x8*)&T[m][s * 32 + quad * 8];

    f32x4 acc[NT];
#pragma unroll
    for (int t = 0; t < NT; t++) acc[t] = (f32x4){0.f, 0.f, 0.f, 0.f};

#pragma unroll
    for (int s = 0; s < 4; s++) {
#pragma unroll
        for (int t = 0; t < NT; t++) {
            const int ct = wv * NT + t;
            f16x8 wf = *(const f16x8*)(Wt + (size_t)(ct * 16 + m) * 128 + s * 32 + quad * 8);
            acc[t] = __builtin_amdgcn_mfma_f32_16x16x32_f16(wf, xf[s], acc[t], 0, 0, 0);
        }
    }

    const int row = base + m;
    if (row < N) {
        float dt = dinv[row];
#pragma unroll
        for (int t = 0; t < NT; t++) {
            const int ct = wv * NT + t;
            const int col0 = ct * 16 + quad * 4;
            f32x4 bv = *(const f32x4*)(bias + col0);
            float v0 = fmaf(dt, acc[t][0], bv[0]);
            float v1 = fmaf(dt, acc[t][1], bv[1]);
            float v2 = fmaf(dt, acc[t][2], bv[2]);
            float v3 = fmaf(dt, acc[t][3], bv[3]);
            if (RELU) {
                v0 = fmaxf(v0, 0.f); v1 = fmaxf(v1, 0.f);
                v2 = fmaxf(v2, 0.f); v3 = fmaxf(v3, 0.f);
            }
            if constexpr (!FINAL) {
                // store As_next = dt * relu(v) as fp16
                __half2 h0 = __floats2half2_rn(dt * v0, dt * v1);
                __half2 h1 = __floats2half2_rn(dt * v2, dt * v3);
                __half2* dstp = (__half2*)((__half*)Outv + (size_t)row * 128 + col0);
                dstp[0] = h0;
                dstp[1] = h1;
            } else {
                f32x4 o;
                o[0] = v0; o[1] = v1; o[2] = v2; o[3] = v3;
                *(f32x4*)((float*)Outv + (size_t)row * 64 + col0) = o;
            }
        }
    }
}

extern "C" void kernel_launch(void* const* d_in, const int* in_sizes, int n_in,
                              void* d_out, int out_size, void* d_ws, size_t ws_size,
                              hipStream_t stream) {
    const int N = in_sizes[0] / 128;   // x is [N,128]
    const int E = in_sizes[2];         // edge_weight is [E]

    const float* x  = (const float*)d_in[0];
    const int*   ei = (const int*)d_in[1];   // [2,E]: row0=src, row1=dst
    const int*   src = ei;
    const int*   dst = ei + E;
    const float* ew  = (const float*)d_in[2];
    const float* W0 = (const float*)d_in[3];
    const float* b0 = (const float*)d_in[4];
    const float* W1 = (const float*)d_in[5];
    const float* b1 = (const float*)d_in[6];
    const float* W2 = (const float*)d_in[7];
    const float* b2 = (const float*)d_in[8];

    // Partitioning: 64-node ranges; widen shift if N is huge so NP<=MAXNP.
    int shift = 6;
    while ((((N - 1) >> shift) + 1) > MAXNP) shift++;
    const int NP = ((N - 1) >> shift) + 1;

    // Workspace carve; bucket capacity adapts so we never write past d_ws.
    size_t fixed = (((size_t)N * 4 + 255) & ~(size_t)255)            // cnt
                 + (((size_t)N * 4 + 255) & ~(size_t)255)            // dinv
                 + 2 * (((size_t)N * 128 * 2 + 255) & ~(size_t)255)  // bufH, bufA fp16
                 + 3 * 33024                                         // wt0,wt1,wt2
                 + (((size_t)NP * 4 + 255) & ~(size_t)255)           // tail
                 + 2048;
    int cap = 64;
    if (ws_size > fixed) {
        size_t avail = (ws_size - fixed) / ((size_t)N * 4);
        if (avail < (size_t)cap) cap = (int)avail;
    } else {
        cap = 0;
    }

    char* p = (char*)d_ws;
    auto alloc = [&](size_t bytes) -> void* {
        void* r = (void*)p;
        p += (bytes + 255) & ~(size_t)255;
        return r;
    };
    int*          cnt  = (int*)alloc((size_t)N * 4);
    float*        dinv = (float*)alloc((size_t)N * 4);
    unsigned int* EW   = (unsigned int*)alloc((size_t)N * cap * 4);
    __half*       bufH = (__half*)alloc((size_t)N * 128 * 2);
    __half*       bufA = (__half*)alloc((size_t)N * 128 * 2);
    __half*       wt0  = (__half*)alloc(16384 * 2);
    __half*       wt1  = (__half*)alloc(16384 * 2);
    __half*       wt2  = (__half*)alloc(8192 * 2);
    int*          tail = (int*)alloc((size_t)NP * 4);

    // Bin lists alias bufA (dead after k_fill; layer-0 writes bufA).
    u64* glist = (u64*)bufA;
    int  ecap  = (int)(((size_t)N * 128 * 2) / ((size_t)NP * 8));  // ~2047 here

    dim3 blk(256);
    dim3 blkBin(1024);
    int preN = (NP > 40960) ? NP : 40960;
    dim3 gPre((preN + 255) / 256);
    dim3 gBin(256);              // 1 block/CU; fixed NP work amortized once
    dim3 gFill(NP);              // 1 block per 64-node partition
    dim3 gLayer((N + 15) / 16);  // 1 block per 16-node MFMA tile

    k_pre<<<gPre, blk, 0, stream>>>(tail, NP, W0, W1, W2, wt0, wt1, wt2);
    k_bin<<<gBin, blkBin, 0, stream>>>(src, dst, ew, tail, glist, E, ecap, NP, shift);
    k_fill<<<gFill, blk, 0, stream>>>(tail, glist, ecap, cnt, dinv, EW, cap, N,
                                      shift, x, bufH);

    // layer 0: gather(As0=bufH) -> @W0 -> As1=bufA
    k_layer<128, true, false><<<gLayer, blk, 0, stream>>>(bufH, EW, cnt, dinv,
                                                          wt0, b0, bufA, N, cap);
    // layer 1: gather(bufA) -> @W1 -> As2=bufH
    k_layer<128, true, false><<<gLayer, blk, 0, stream>>>(bufA, EW, cnt, dinv,
                                                          wt1, b1, bufH, N, cap);
    // layer 2: gather(bufH) -> @W2 -> out fp32 (no relu)
    k_layer<64, false, true><<<gLayer, blk, 0, stream>>>(bufH, EW, cnt, dinv,
                                                         wt2, b2, d_out, N, cap);
}

// Round 18
// 397.318 us; speedup vs baseline: 1.1720x; 1.0006x over previous
//
#include <hip/hip_runtime.h>
#include <hip/hip_fp16.h>

// GCN 3-layer encoder for MI355X — R18: REVERT to R15-exact (397.6us, the
// best verified kernel). R16/R17 post-mortem: the k_layer weight-decode
// hoist fails correctness (0.107 single-launch / 468 graph-path) despite
// bit-equivalence on paper -- launch-mode-dependent magnitude says it
// exposes a latent codegen/timing sensitivity; refuted empirically, reverted.
// Terminal accounting (R4-R15 ladder): 3x layer gathers at the TA floor
// (~13 cyc/edge, invariant to bytes/lines/MLP/instr-count: R6/R8/R9 nulls)
// ~= 206us; bin+fill ~= 65us (R15 occupancy fix); dispatch overhead 50-80us
// (R11 zero-gap bracket). Grid-barrier fusion (R10/R11) and global-RMW
// builds (R3) are refuted paths.
// Layers (R13): gather T[16][128] in LDS -> MFMA U=T@W -> fused epilogue;
// associativity out = (S*A)*W + b deletes standalone gemms.
// k_pre -> k_bin(256x1024) -> k_fill(+As0) -> k_layer x3

typedef __attribute__((ext_vector_type(8))) _Float16 f16x8;
typedef __attribute__((ext_vector_type(4))) float f32x4;
typedef unsigned long long u64;

#define WQ_BITS 15
#define WQ_SCALE 32768.0f
#define WQ_MASK 32767u
#define MAXNP 2048
#define TSTR 136  // LDS T row stride in halfs (272B: 16B-aligned, non-pow2)

#define SHFLU(v, k) ((unsigned int)__shfl((int)(v), (k), 64))

// Fused: zero tails + transpose W0/W1/W2 (fp32 [k][n]) into f16 Wt [n][k].
__global__ __launch_bounds__(256) void k_pre(int* tail, int NP,
                                             const float* __restrict__ W0,
                                             const float* __restrict__ W1,
                                             const float* __restrict__ W2,
                                             __half* __restrict__ wt0,
                                             __half* __restrict__ wt1,
                                             __half* __restrict__ wt2) {
    int id = blockIdx.x * 256 + threadIdx.x;
    if (id < NP) tail[id] = 0;
    if (id < 16384) {
        int n = id >> 7, k = id & 127;
        wt0[id] = __float2half(W0[k * 128 + n]);
    } else if (id < 32768) {
        int j = id - 16384, n = j >> 7, k = j & 127;
        wt1[j] = __float2half(W1[k * 128 + n]);
    } else if (id < 40960) {
        int j = id - 32768, n = j >> 7, k = j & 127;  // n in [0,64)
        wt2[j] = __float2half(W2[k * 64 + n]);
    }
}

// Phase 1: bin edges into NP per-node-range lists. 256 blocks (fixed NP
// work amortized once) x 1024 threads (16 waves/CU for latency hiding).
// Two passes over a contiguous per-block chunk (2nd pass L2-hot).
__global__ __launch_bounds__(1024) void k_bin(const int* __restrict__ src,
                                              const int* __restrict__ dst,
                                              const float* __restrict__ w,
                                              int* tail, u64* __restrict__ glist,
                                              int E, int ecap, int NP, int shift) {
    __shared__ unsigned int h[MAXNP];
    __shared__ int base[MAXNP];
    const int tid = threadIdx.x;
    const int nb = gridDim.x;
    const int per = (E + nb - 1) / nb;
    const int e0 = blockIdx.x * per;
    const int e1 = (e0 + per < E) ? e0 + per : E;

    for (int i = tid; i < NP; i += 1024) h[i] = 0;
    __syncthreads();
    for (int e = e0 + tid; e < e1; e += 1024) {
        int p = dst[e] >> shift;
        atomicAdd(&h[p], 1u);
    }
    __syncthreads();
    for (int i = tid; i < NP; i += 1024) {
        unsigned int c = h[i];
        base[i] = c ? atomicAdd(&tail[i], (int)c) : 0;
    }
    __syncthreads();
    for (int e = e0 + tid; e < e1; e += 1024) {
        int t = dst[e];  // L2-hot (pass 1 cached it)
        int p = t >> shift;
        int s = __builtin_nontemporal_load(src + e);
        float we = __builtin_nontemporal_load(w + e);
        int wq = (int)(we * WQ_SCALE + 0.5f);
        wq = (wq < (int)WQ_MASK) ? wq : (int)WQ_MASK;
        u64 v = ((u64)(unsigned)t << 32) |
                ((unsigned)s << WQ_BITS) | (unsigned)wq;
        unsigned int idx = atomicSub(&h[p], 1u) - 1u;  // LDS, order-free
        int pos = base[p] + (int)idx;
        if (pos < ecap) glist[(size_t)p * ecap + pos] = v;
    }
}

// Phase 2: one block per 64-node partition. LDS slot counters; EW plain
// stores; cnt + dinv; then As0 = dinv * x as fp16 (the layer-0 prescaled
// input -- replaces the old fused gemm0 entirely).
__global__ __launch_bounds__(256) void k_fill(const int* __restrict__ tail,
                                              const u64* __restrict__ glist,
                                              int ecap, int* __restrict__ cnt,
                                              float* __restrict__ dinv,
                                              unsigned int* __restrict__ EW,
                                              int cap, int N, int shift,
                                              const float* __restrict__ X,
                                              __half* __restrict__ As0) {
    __shared__ unsigned int lcnt[MAXNP];
    __shared__ float lws[MAXNP];
    const int p = blockIdx.x;
    const int np = 1 << shift;
    const int t0 = p << shift;

    for (int i = threadIdx.x; i < np; i += 256) { lcnt[i] = 0; lws[i] = 0.f; }
    __syncthreads();
    int n = tail[p];
    if (n > ecap) n = ecap;
    const u64* L = glist + (size_t)p * ecap;
    for (int j = threadIdx.x; j < n; j += 256) {
        u64 v = L[j];
        int t = (int)(v >> 32);
        int loc = t - t0;
        unsigned int k = atomicAdd(&lcnt[loc], 1u);  // LDS
        if ((int)k < cap) {
            EW[(size_t)t * cap + k] = (unsigned int)v;
            atomicAdd(&lws[loc], (float)((unsigned int)v & WQ_MASK));  // LDS f32
        }
    }
    __syncthreads();
    for (int i = threadIdx.x; i < np; i += 256) {
        int t = t0 + i;
        float dv = 1.0f / sqrtf(1.0f + lws[i] * (1.0f / WQ_SCALE));
        if (t < N) {
            int c = (int)lcnt[i];
            c = (c < cap) ? c : cap;
            cnt[t] = c;
            dinv[t] = dv;
        }
        lws[i] = dv;  // hand dinv to the As0 stage via LDS
    }
    __syncthreads();

    // As0 = dinv * x (fp32 -> fp16), 4 threads per row, 32 cols each.
    for (int rb = 0; rb < np; rb += 64) {
        int rloc = rb + (int)(threadIdx.x >> 2);
        int sub = threadIdx.x & 3;
        int r = t0 + rloc;
        if (rloc < np && r < N) {
            float dv = lws[rloc];
#pragma unroll
            for (int cc = 0; cc < 4; cc++) {
                int c0 = sub * 32 + cc * 8;
                float4 u0 = *(const float4*)(X + (size_t)r * 128 + c0);
                float4 u1 = *(const float4*)(X + (size_t)r * 128 + c0 + 4);
                f16x8 f;
                f[0] = (_Float16)(dv * u0.x); f[1] = (_Float16)(dv * u0.y);
                f[2] = (_Float16)(dv * u0.z); f[3] = (_Float16)(dv * u0.w);
                f[4] = (_Float16)(dv * u1.x); f[5] = (_Float16)(dv * u1.y);
                f[6] = (_Float16)(dv * u1.z); f[7] = (_Float16)(dv * u1.w);
                *(f16x8*)(As0 + (size_t)r * 128 + c0) = f;
            }
        }
    }
}

// Fused layer: block = 16 nodes. Phase A: 4 waves gather T rows (R9 packed
// gather: 4 edges per dwordx4 instruction) into LDS. Phase B: MFMA U = T@W
// (k_gemm-verbatim fragment indexing; waves split columns) with fused
// epilogue: v = dt*U + b; [relu]; store fp16 dt*v (As_next) or fp32 v (out).
template <int BNO, bool RELU, bool FINAL>
__global__ __launch_bounds__(256) void k_layer(const __half* __restrict__ As,
                                               const unsigned int* __restrict__ EW,
                                               const int* __restrict__ cnt,
                                               const float* __restrict__ dinv,
                                               const __half* __restrict__ Wt,
                                               const float* __restrict__ bias,
                                               void* __restrict__ Outv,
                                               int N, int cap) {
    __shared__ __align__(16) __half T[16][TSTR];
    const int tid = threadIdx.x;
    const int lane = tid & 63;
    const int wv = tid >> 6;
    const int base = blockIdx.x * 16;

    // zero T (OOB rows must be 0 for the MFMA phase)
    for (int i = tid; i < 16 * TSTR; i += 256) ((__half*)T)[i] = (__half)0.f;
    __syncthreads();

    // ---- Phase A: gather. Wave wv owns nodes base + wv*4 + {0..3}. ----
    const int part = lane & 15;  // 16B chunk of the 256B row
    const int q = lane >> 4;     // edge within group of 4
    for (int i = 0; i < 4; i++) {
        const int rloc = wv * 4 + i;
        const int node = base + rloc;
        if (node < N) {
            int c = cnt[node];
            c = (c < cap) ? c : cap;
            unsigned int meta = 0;
            if (lane < c) meta = EW[(size_t)node * cap + lane];

            float acc[8];
#pragma unroll
            for (int j = 0; j < 8; j++) acc[j] = 0.f;

            int k = 0;
            for (; k + 16 <= c; k += 16) {
                f16x8 hv[4];
                float w[4];
#pragma unroll
                for (int g = 0; g < 4; g++) {
                    unsigned int mm = SHFLU(meta, k + g * 4 + q);
                    w[g] = (float)(mm & WQ_MASK) * (1.0f / WQ_SCALE);
                    hv[g] = *(const f16x8*)(As + (size_t)(mm >> WQ_BITS) * 128 + part * 8);
                }
#pragma unroll
                for (int g = 0; g < 4; g++)
#pragma unroll
                    for (int j = 0; j < 8; j++)
                        acc[j] = fmaf(w[g], (float)hv[g][j], acc[j]);
            }
            for (; k < c; k += 4) {
                int idx = k + q;
                unsigned int mm = SHFLU(meta, (idx < c) ? idx : 0);
                float w = (idx < c) ? (float)(mm & WQ_MASK) * (1.0f / WQ_SCALE) : 0.f;
                unsigned int row = (idx < c) ? (mm >> WQ_BITS) : (unsigned int)node;
                f16x8 hv = *(const f16x8*)(As + (size_t)row * 128 + part * 8);
#pragma unroll
                for (int j = 0; j < 8; j++)
                    acc[j] = fmaf(w, (float)hv[j], acc[j]);
            }
#pragma unroll
            for (int j = 0; j < 8; j++) {
                acc[j] += __shfl_xor(acc[j], 16, 64);
                acc[j] += __shfl_xor(acc[j], 32, 64);
            }
            if (q == 0) {
                f16x8 sv = *(const f16x8*)(As + (size_t)node * 128 + part * 8);
                f16x8 tv;
#pragma unroll
                for (int j = 0; j < 8; j++)
                    tv[j] = (_Float16)(acc[j] + (float)sv[j]);
                *(f16x8*)&T[rloc][part * 8] = tv;
            }
        }
    }
    __syncthreads();

    // ---- Phase B: U = T @ W via MFMA (k_gemm-verbatim indexing). ----
    const int m = lane & 15;
    const int quad = lane >> 4;
    constexpr int NT = (BNO == 128) ? 2 : 1;  // col-tiles per wave (x4 waves)

    f16x8 xf[4];
#pragma unroll
    for (int s = 0; s < 4; s++)
        xf[s] = *(const f16x8*)&T[m][s * 32 + quad * 8];

    f32x4 acc[NT];
#pragma unroll
    for (int t = 0; t < NT; t++) acc[t] = (f32x4){0.f, 0.f, 0.f, 0.f};

#pragma unroll
    for (int s = 0; s < 4; s++) {
#pragma unroll
        for (int t = 0; t < NT; t++) {
            const int ct = wv * NT + t;
            f16x8 wf = *(const f16x8*)(Wt + (size_t)(ct * 16 + m) * 128 + s * 32 + quad * 8);
            acc[t] = __builtin_amdgcn_mfma_f32_16x16x32_f16(wf, xf[s], acc[t], 0, 0, 0);
        }
    }

    const int row = base + m;
    if (row < N) {
        float dt = dinv[row];
#pragma unroll
        for (int t = 0; t < NT; t++) {
            const int ct = wv * NT + t;
            const int col0 = ct * 16 + quad * 4;
            f32x4 bv = *(const f32x4*)(bias + col0);
            float v0 = fmaf(dt, acc[t][0], bv[0]);
            float v1 = fmaf(dt, acc[t][1], bv[1]);
            float v2 = fmaf(dt, acc[t][2], bv[2]);
            float v3 = fmaf(dt, acc[t][3], bv[3]);
            if (RELU) {
                v0 = fmaxf(v0, 0.f); v1 = fmaxf(v1, 0.f);
                v2 = fmaxf(v2, 0.f); v3 = fmaxf(v3, 0.f);
            }
            if constexpr (!FINAL) {
                // store As_next = dt * relu(v) as fp16
                __half2 h0 = __floats2half2_rn(dt * v0, dt * v1);
                __half2 h1 = __floats2half2_rn(dt * v2, dt * v3);
                __half2* dstp = (__half2*)((__half*)Outv + (size_t)row * 128 + col0);
                dstp[0] = h0;
                dstp[1] = h1;
            } else {
                f32x4 o;
                o[0] = v0; o[1] = v1; o[2] = v2; o[3] = v3;
                *(f32x4*)((float*)Outv + (size_t)row * 64 + col0) = o;
            }
        }
    }
}

extern "C" void kernel_launch(void* const* d_in, const int* in_sizes, int n_in,
                              void* d_out, int out_size, void* d_ws, size_t ws_size,
                              hipStream_t stream) {
    const int N = in_sizes[0] / 128;   // x is [N,128]
    const int E = in_sizes[2];         // edge_weight is [E]

    const float* x  = (const float*)d_in[0];
    const int*   ei = (const int*)d_in[1];   // [2,E]: row0=src, row1=dst
    const int*   src = ei;
    const int*   dst = ei + E;
    const float* ew  = (const float*)d_in[2];
    const float* W0 = (const float*)d_in[3];
    const float* b0 = (const float*)d_in[4];
    const float* W1 = (const float*)d_in[5];
    const float* b1 = (const float*)d_in[6];
    const float* W2 = (const float*)d_in[7];
    const float* b2 = (const float*)d_in[8];

    // Partitioning: 64-node ranges; widen shift if N is huge so NP<=MAXNP.
    int shift = 6;
    while ((((N - 1) >> shift) + 1) > MAXNP) shift++;
    const int NP = ((N - 1) >> shift) + 1;

    // Workspace carve; bucket capacity adapts so we never write past d_ws.
    size_t fixed = (((size_t)N * 4 + 255) & ~(size_t)255)            // cnt
                 + (((size_t)N * 4 + 255) & ~(size_t)255)            // dinv
                 + 2 * (((size_t)N * 128 * 2 + 255) & ~(size_t)255)  // bufH, bufA fp16
                 + 3 * 33024                                         // wt0,wt1,wt2
                 + (((size_t)NP * 4 + 255) & ~(size_t)255)           // tail
                 + 2048;
    int cap = 64;
    if (ws_size > fixed) {
        size_t avail = (ws_size - fixed) / ((size_t)N * 4);
        if (avail < (size_t)cap) cap = (int)avail;
    } else {
        cap = 0;
    }

    char* p = (char*)d_ws;
    auto alloc = [&](size_t bytes) -> void* {
        void* r = (void*)p;
        p += (bytes + 255) & ~(size_t)255;
        return r;
    };
    int*          cnt  = (int*)alloc((size_t)N * 4);
    float*        dinv = (float*)alloc((size_t)N * 4);
    unsigned int* EW   = (unsigned int*)alloc((size_t)N * cap * 4);
    __half*       bufH = (__half*)alloc((size_t)N * 128 * 2);
    __half*       bufA = (__half*)alloc((size_t)N * 128 * 2);
    __half*       wt0  = (__half*)alloc(16384 * 2);
    __half*       wt1  = (__half*)alloc(16384 * 2);
    __half*       wt2  = (__half*)alloc(8192 * 2);
    int*          tail = (int*)alloc((size_t)NP * 4);

    // Bin lists alias bufA (dead after k_fill; layer-0 writes bufA).
    u64* glist = (u64*)bufA;
    int  ecap  = (int)(((size_t)N * 128 * 2) / ((size_t)NP * 8));  // ~2047 here

    dim3 blk(256);
    dim3 blkBin(1024);
    int preN = (NP > 40960) ? NP : 40960;
    dim3 gPre((preN + 255) / 256);
    dim3 gBin(256);              // 1 block/CU; fixed NP work amortized once
    dim3 gFill(NP);              // 1 block per 64-node partition
    dim3 gLayer((N + 15) / 16);  // 1 block per 16-node MFMA tile

    k_pre<<<gPre, blk, 0, stream>>>(tail, NP, W0, W1, W2, wt0, wt1, wt2);
    k_bin<<<gBin, blkBin, 0, stream>>>(src, dst, ew, tail, glist, E, ecap, NP, shift);
    k_fill<<<gFill, blk, 0, stream>>>(tail, glist, ecap, cnt, dinv, EW, cap, N,
                                      shift, x, bufH);

    // layer 0: gather(As0=bufH) -> @W0 -> As1=bufA
    k_layer<128, true, false><<<gLayer, blk, 0, stream>>>(bufH, EW, cnt, dinv,
                                                          wt0, b0, bufA, N, cap);
    // layer 1: gather(bufA) -> @W1 -> As2=bufH
    k_layer<128, true, false><<<gLayer, blk, 0, stream>>>(bufA, EW, cnt, dinv,
                                                          wt1, b1, bufH, N, cap);
    // layer 2: gather(bufH) -> @W2 -> out fp32 (no relu)
    k_layer<64, false, true><<<gLayer, blk, 0, stream>>>(bufH, EW, cnt, dinv,
                                                         wt2, b2, d_out, N, cap);
}